// Round 2
// baseline (295.345 us; speedup 1.0000x reference)
//
#include <hip/hip_runtime.h>
#include <hip/hip_fp16.h>

#define NN  25000
#define EE  500000
#define BB  4
#define DD  32
#define LL  4
#define R2C 474
#define BD  128      // B*D
#define THD 416      // 13*D
#define EPSF 1e-6f
#define WMH 13312    // halfs per layer of MFMA-packed W: 13 t * 2 nt * 64 * 8
#define CAP 64       // fixed CSR segment capacity (max degree ~40 for Poisson(20))

// merged build+setup grid partition
#define NEB    1954  // ceil(EE / 256), 1 edge/thread
#define NWMB   208   // LL*WMH / 256
#define NRELIN 948   // LL*R2C*BD / 256
#define NW1P   16    // 4096 / 256

typedef _Float16 half8 __attribute__((ext_vector_type(8)));
typedef float    f32x4 __attribute__((ext_vector_type(4)));

// ---------------- merged graph build + all query-side setup ----------------
// blocks [0,NEB)        : per-edge count/slot atomic + direct CSR scatter + wsum
// blocks [NEB,+NWMB)    : pack lin_W into MFMA B-fragment order (fp16)
// blocks [..,+NRELIN)   : rel_in for ALL layers (query recomputed inline)
// blocks [..,+NW1P)     : pack mlp_W1 into MFMA B-fragment order (fp16)
// last block            : query gather
__global__ __launch_bounds__(256) void build_setup_kernel(
    const int* __restrict__ node_in, const int* __restrict__ node_out,
    const int* __restrict__ relation, const float* __restrict__ ew,
    int* __restrict__ cnt, float* __restrict__ wsum, int2* __restrict__ ep,
    const float* __restrict__ linW, _Float16* __restrict__ Wm,
    const int* __restrict__ r_index, const float* __restrict__ qemb,
    const float* __restrict__ relW, const float* __restrict__ relB,
    __half* __restrict__ relIn, float* __restrict__ query,
    const float* __restrict__ W1, _Float16* __restrict__ W1m) {
  const int blk = blockIdx.x;
  const int tid = threadIdx.x;
  if (blk < NEB) {
    int i = blk * 256 + tid;
    if (i >= EE) return;
    int d = node_out[i];
    float w = ew[i];
    int slot = atomicAdd(&cnt[d], 1);            // returning: feeds store only
    atomicAdd(&wsum[d], w);                      // fire-and-forget
    ep[d * CAP + slot] = make_int2(node_in[i] | (relation[i] << 15),
                                   __float_as_int(w));
  } else if (blk < NEB + NWMB) {
    int idx = (blk - NEB) * 256 + tid;           // < LL*WMH exactly
    int l = idx / WMH, rest = idx % WMH;
    int t = rest >> 10;
    int nt = (rest >> 9) & 1;
    int L = (rest >> 3) & 63;
    int j = rest & 7;
    int k = t * 32 + (L >> 4) * 8 + j;
    int n = nt * 16 + (L & 15);
    int wrow;
    if (k < 32) wrow = k;
    else {
      int kk = k - 32;
      int slab = kk >> 7, s = (kk >> 5) & 3, dd = kk & 31;
      wrow = DD + (dd * 4 + s) * 3 + slab;
    }
    Wm[idx] = (_Float16)linW[(size_t)l * THD * DD + (size_t)wrow * DD + n];
  } else if (blk < NEB + NWMB + NRELIN) {
    int o = (blk - NEB - NWMB) * 256 + tid;      // < LL*R2C*BD exactly
    int l = o / (R2C * BD);
    int rest = o % (R2C * BD);
    int r = rest >> 7, b = (rest >> 5) & 3, d = rest & 31;
    int col = r * DD + d;
    const float* W = relW + (size_t)l * DD * R2C * DD;
    const float* qrow = qemb + (size_t)r_index[b] * DD;
    float acc = relB[(size_t)l * R2C * DD + col];
    #pragma unroll
    for (int k = 0; k < DD; ++k)
      acc = fmaf(qrow[k], W[(size_t)k * (R2C * DD) + col], acc);
    relIn[o] = __float2half(acc);
  } else if (blk < NEB + NWMB + NRELIN + NW1P) {
    int idx = (blk - NEB - NWMB - NRELIN) * 256 + tid;  // < 4096 exactly
    int kc = idx >> 11;
    int nt = (idx >> 9) & 3;
    int L = (idx >> 3) & 63;
    int j = idx & 7;
    int k = kc * 32 + (L >> 4) * 8 + j;          // feat row 0..63
    int c = nt * 16 + (L & 15);                  // out col 0..63
    W1m[idx] = (_Float16)W1[(size_t)k * (2 * DD) + c];
  } else {
    if (tid < BD) query[tid] = qemb[(size_t)r_index[tid >> 5] * DD + (tid & 31)];
  }
}

// log-degree + logsum reduce (needs complete wsum)
__global__ __launch_bounds__(256) void lg_kernel(const float* __restrict__ wsum,
                                                 float* __restrict__ lg,
                                                 float* __restrict__ logsum) {
  int n = blockIdx.x * 256 + threadIdx.x;
  float v = 0.f;
  if (n < NN) {
    v = logf(wsum[n] + 1.0f);
    lg[n] = v;
  }
  __shared__ float red[256];
  red[threadIdx.x] = v; __syncthreads();
  for (int o = 128; o > 0; o >>= 1) {
    if (threadIdx.x < o) red[threadIdx.x] += red[threadIdx.x + o];
    __syncthreads();
  }
  if (threadIdx.x == 0) atomicAdd(logsum, red[0]);
}

// ---- shared MFMA epilogue: one wave computes 16x32 linear for 4 nodes ----
// sh layout: [nl][s*128 + b*32 + d] halfs (s = mean,max,min,std).
// hzero: if true, t=0 A-fragment is analytic boundary (layer 1).
// LAST: fuse the final MLP (feat=[hidden,query] -> relu(64) -> 1) and write
//       scores directly; skip the hidden store.
template <bool LAST>
__device__ __forceinline__ void mfma_epilogue(const _Float16* sh,
                                              const _Float16* hinh,
                                              __half* houth,
                                              const float* lg,
                                              const float* logsum,
                                              const _Float16* Wm,
                                              const float* bias,
                                              const float* query,
                                              const int* h_index,
                                              int nbase, int lane, bool hzero,
                                              const _Float16* W1m,
                                              const float* b1,
                                              const float* W2,
                                              const float* b2,
                                              float* out,
                                              _Float16* hbuf) {
  const int m = lane & 15;
  const int q = lane >> 4;
  const int nl = m >> 2;
  const int n = nbase + nl;
  const int b = m & 3;
  const float sc = lg[n] * ((float)NN / logsum[0]);
  const _Float16 one = (_Float16)1.f;
  const _Float16 s1h = (_Float16)sc;
  const _Float16 s2h = (_Float16)(1.0f / fmaxf(sc, 0.01f));
  const _Float16* ssrc = sh + nl * 512 + b * 32 + q * 8;

  f32x4 c0 = {0.f, 0.f, 0.f, 0.f};
  f32x4 c1 = {0.f, 0.f, 0.f, 0.f};
  half8 a;
  if (hzero) {
    a = (half8)(_Float16)0.f;
    if (n == h_index[b]) {
      const float* qp = query + b * 32 + q * 8;
      #pragma unroll
      for (int j = 0; j < 8; ++j) a[j] = (_Float16)qp[j];
    }
  } else {
    a = *(const half8*)(hinh + (unsigned)n * BD + b * 32 + q * 8);
  }
  #pragma unroll
  for (int t = 0; t < 13; ++t) {
    if (t > 0) {
      const int slab = (t - 1) >> 2, s = (t - 1) & 3;
      a = *(const half8*)(ssrc + s * 128);
      const _Float16 sch = (slab == 0) ? one : ((slab == 1) ? s1h : s2h);
      half8 sv = {sch, sch, sch, sch, sch, sch, sch, sch};
      a = a * sv;
    }
    half8 b0 = *(const half8*)(Wm + (unsigned)(t * 2 + 0) * 512 + lane * 8);
    half8 b1f = *(const half8*)(Wm + (unsigned)(t * 2 + 1) * 512 + lane * 8);
    c0 = __builtin_amdgcn_mfma_f32_16x16x32_f16(a, b0, c0, 0, 0, 0);
    c1 = __builtin_amdgcn_mfma_f32_16x16x32_f16(a, b1f, c1, 0, 0, 0);
  }
  const int col = lane & 15;
  const float bj0 = bias[col], bj1 = bias[col + 16];
  if constexpr (!LAST) {
    #pragma unroll
    for (int i = 0; i < 4; ++i) {
      const int mr = q * 4 + i;
      __half* dst = houth + (unsigned)(nbase + (mr >> 2)) * BD + (mr & 3) * 32 + col;
      dst[0]  = __float2half(fmaxf(c0[i] + bj0, 0.f));
      dst[16] = __float2half(fmaxf(c1[i] + bj1, 0.f));
    }
  } else {
    // stage relu'd hidden (C-layout) into LDS for transpose into A-layout
    #pragma unroll
    for (int i = 0; i < 4; ++i) {
      const int mr = q * 4 + i;
      hbuf[mr * 32 + col]      = (_Float16)fmaxf(c0[i] + bj0, 0.f);
      hbuf[mr * 32 + 16 + col] = (_Float16)fmaxf(c1[i] + bj1, 0.f);
    }
    // A-fragment reads: row = lane&15 (node,b), k = q*8+j
    half8 ah = *(const half8*)(hbuf + m * 32 + q * 8);
    half8 aq;
    const float* qp = query + b * 32 + q * 8;
    #pragma unroll
    for (int j = 0; j < 8; ++j) aq[j] = (_Float16)qp[j];
    f32x4 h1c[4];
    #pragma unroll
    for (int nt = 0; nt < 4; ++nt) {
      h1c[nt] = (f32x4){0.f, 0.f, 0.f, 0.f};
      half8 w0 = *(const half8*)(W1m + (unsigned)(0 * 4 + nt) * 512 + lane * 8);
      half8 w1 = *(const half8*)(W1m + (unsigned)(1 * 4 + nt) * 512 + lane * 8);
      h1c[nt] = __builtin_amdgcn_mfma_f32_16x16x32_f16(ah, w0, h1c[nt], 0, 0, 0);
      h1c[nt] = __builtin_amdgcn_mfma_f32_16x16x32_f16(aq, w1, h1c[nt], 0, 0, 0);
    }
    float part[4] = {0.f, 0.f, 0.f, 0.f};
    #pragma unroll
    for (int nt = 0; nt < 4; ++nt) {
      const float bb = b1[nt * 16 + col];
      const float ww = W2[nt * 16 + col];
      #pragma unroll
      for (int i = 0; i < 4; ++i) {
        float v = fmaxf(h1c[nt][i] + bb, 0.f);
        part[i] = fmaf(v, ww, part[i]);
      }
    }
    #pragma unroll
    for (int i = 0; i < 4; ++i) {
      part[i] += __shfl_xor(part[i], 1);
      part[i] += __shfl_xor(part[i], 2);
      part[i] += __shfl_xor(part[i], 4);
      part[i] += __shfl_xor(part[i], 8);
    }
    if (col == 0) {
      const float b2v = b2[0];
      #pragma unroll
      for (int i = 0; i < 4; ++i)
        out[(unsigned)i * NN + nbase + q] = part[i] + b2v;
    }
  }
}

// ---------------- fused layer 1: analytic sparse gather + MFMA linear ------
__global__ __launch_bounds__(256) void layer1_fused_kernel(
    const __half2* __restrict__ rel2, const int2* __restrict__ ep,
    const int* __restrict__ cnt, const int* __restrict__ h_index,
    const float* __restrict__ query, const float* __restrict__ lg,
    const float* __restrict__ logsum, const _Float16* __restrict__ Wm,
    const float* __restrict__ bias, __half* __restrict__ houth) {
  __shared__ __align__(16) __half2 sh[4][256];   // [wave][s*64 + lane]
  const int lane = threadIdx.x & 63;
  const int wid  = threadIdx.x >> 6;
  const int nbase = blockIdx.x * 4;
  const int n = nbase + wid;
  const int b = lane >> 4;
  const int d0 = (lane & 15) * 2;
  const float q0 = query[b * 32 + d0], q1 = query[b * 32 + d0 + 1];
  const int hb = h_index[b];
  const int beg = n * CAP;
  const int cnn = __builtin_amdgcn_readfirstlane(cnt[n]);
  const float mb0 = (n == hb) ? q0 : 0.f;
  const float mb1 = (n == hb) ? q1 : 0.f;
  float sa0 = mb0, qa0 = mb0 * mb0, mx0 = mb0, mn0 = mb0;
  float sa1 = mb1, qa1 = mb1 * mb1, mx1 = mb1, mn1 = mb1;
  int matched = 0;
  for (int p = beg; p < beg + cnn; ++p) {
    int2 e = ep[p];
    if ((e.x & 0x7fff) == hb) {
      __half2 rv = rel2[(unsigned)((unsigned)e.x >> 15) * 64 + lane];
      float w = __int_as_float(e.y);
      float2 rf = __half22float2(rv);
      float m0 = rf.x * q0, mw0 = m0 * w;
      float m1 = rf.y * q1, mw1 = m1 * w;
      sa0 += mw0; qa0 = fmaf(m0, mw0, qa0); mx0 = fmaxf(mx0, mw0); mn0 = fminf(mn0, mw0);
      sa1 += mw1; qa1 = fmaf(m1, mw1, qa1); mx1 = fmaxf(mx1, mw1); mn1 = fminf(mn1, mw1);
      ++matched;
    }
  }
  if (matched < cnn) {
    mx0 = fmaxf(mx0, 0.f); mn0 = fminf(mn0, 0.f);
    mx1 = fmaxf(mx1, 0.f); mn1 = fminf(mn1, 0.f);
  }
  const float invc = 1.0f / (float)(cnn + 1);
  const float mean0 = sa0 * invc, mean1 = sa1 * invc;
  const float sd0 = sqrtf(fmaxf(qa0 * invc - mean0 * mean0, EPSF));
  const float sd1 = sqrtf(fmaxf(qa1 * invc - mean1 * mean1, EPSF));
  sh[wid][lane]       = __floats2half2_rn(mean0, mean1);
  sh[wid][64 + lane]  = __floats2half2_rn(mx0, mx1);
  sh[wid][128 + lane] = __floats2half2_rn(mn0, mn1);
  sh[wid][192 + lane] = __floats2half2_rn(sd0, sd1);
  __syncthreads();
  if (threadIdx.x >= 64) return;
  mfma_epilogue<false>((const _Float16*)&sh[0][0], nullptr, houth, lg, logsum,
                       Wm, bias, query, h_index, nbase, lane, true,
                       nullptr, nullptr, nullptr, nullptr, nullptr, nullptr);
}

// ---------------- fused generic layer: gather + MFMA linear ----------------
template <bool LAST>
__global__ __launch_bounds__(256) void layer_fused_kernel(
    const __half2* __restrict__ hin2, const __half2* __restrict__ rel2,
    const int2* __restrict__ ep, const int* __restrict__ cnt,
    const int* __restrict__ h_index, const float* __restrict__ query,
    const float* __restrict__ lg, const float* __restrict__ logsum,
    const _Float16* __restrict__ Wm, const float* __restrict__ bias,
    __half* __restrict__ houth,
    const _Float16* __restrict__ W1m, const float* __restrict__ b1,
    const float* __restrict__ W2, const float* __restrict__ b2,
    float* __restrict__ out) {
  __shared__ __align__(16) __half2 sh[4][256];
  __shared__ __align__(16) _Float16 hbuf[512];
  const int lane = threadIdx.x & 63;
  const int wid  = threadIdx.x >> 6;
  const int nbase = blockIdx.x * 4;
  const int n = nbase + wid;
  const int b = lane >> 4;
  const int d0 = (lane & 15) * 2;
  const float q0 = query[b * 32 + d0], q1 = query[b * 32 + d0 + 1];
  const int hb = h_index[b];
  const int beg = n * CAP;
  const int cnn = __builtin_amdgcn_readfirstlane(cnt[n]);
  const float mb0 = (n == hb) ? q0 : 0.f;
  const float mb1 = (n == hb) ? q1 : 0.f;
  float sa0 = mb0, qa0 = mb0 * mb0, mx0 = mb0, mn0 = mb0;
  float sa1 = mb1, qa1 = mb1 * mb1, mx1 = mb1, mn1 = mb1;

#define PROC(Ez, Hv, Rv) {                                                   \
    float w = __int_as_float(Ez);                                            \
    float2 hf = __half22float2(Hv), rf = __half22float2(Rv);                 \
    float m0 = rf.x * hf.x, mw0 = m0 * w;                                    \
    float m1 = rf.y * hf.y, mw1 = m1 * w;                                    \
    sa0 += mw0; qa0 = fmaf(m0, mw0, qa0);                                    \
    mx0 = fmaxf(mx0, mw0); mn0 = fminf(mn0, mw0);                            \
    sa1 += mw1; qa1 = fmaf(m1, mw1, qa1);                                    \
    mx1 = fmaxf(mx1, mw1); mn1 = fminf(mn1, mw1); }
#define ROWS(Ex, Hd, Rd) {                                                   \
    Hd = hin2[(unsigned)((Ex) & 0x7fff) * 64 + lane];                        \
    Rd = rel2[(unsigned)((unsigned)(Ex) >> 15) * 64 + lane]; }

  int p = beg;
  int rem = cnn;
  const int nb = rem >> 3;
  if (nb > 0) {
    int2 E0, E1, E2, E3, E4, E5, E6, E7;
    __half2 H0, H1, H2, H3, H4, H5, H6, H7;
    __half2 R0, R1, R2, R3, R4, R5, R6, R7;
    E0 = ep[p];     E1 = ep[p + 1]; E2 = ep[p + 2]; E3 = ep[p + 3];
    E4 = ep[p + 4]; E5 = ep[p + 5]; E6 = ep[p + 6]; E7 = ep[p + 7];
    ROWS(E0.x, H0, R0); ROWS(E1.x, H1, R1); ROWS(E2.x, H2, R2); ROWS(E3.x, H3, R3);
    ROWS(E4.x, H4, R4); ROWS(E5.x, H5, R5); ROWS(E6.x, H6, R6); ROWS(E7.x, H7, R7);
    for (int it = 1; it < nb; ++it) {
      const int pn = p + 8;
      int2 F0 = ep[pn],     F1 = ep[pn + 1], F2 = ep[pn + 2], F3 = ep[pn + 3];
      int2 F4 = ep[pn + 4], F5 = ep[pn + 5], F6 = ep[pn + 6], F7 = ep[pn + 7];
      __half2 G0, G1, G2, G3, G4, G5, G6, G7;
      __half2 S0, S1, S2, S3, S4, S5, S6, S7;
      ROWS(F0.x, G0, S0); ROWS(F1.x, G1, S1); ROWS(F2.x, G2, S2); ROWS(F3.x, G3, S3);
      ROWS(F4.x, G4, S4); ROWS(F5.x, G5, S5); ROWS(F6.x, G6, S6); ROWS(F7.x, G7, S7);
      PROC(E0.y, H0, R0); PROC(E1.y, H1, R1); PROC(E2.y, H2, R2); PROC(E3.y, H3, R3);
      PROC(E4.y, H4, R4); PROC(E5.y, H5, R5); PROC(E6.y, H6, R6); PROC(E7.y, H7, R7);
      E0 = F0; E1 = F1; E2 = F2; E3 = F3; E4 = F4; E5 = F5; E6 = F6; E7 = F7;
      H0 = G0; H1 = G1; H2 = G2; H3 = G3; H4 = G4; H5 = G5; H6 = G6; H7 = G7;
      R0 = S0; R1 = S1; R2 = S2; R3 = S3; R4 = S4; R5 = S5; R6 = S6; R7 = S7;
      p = pn;
    }
    PROC(E0.y, H0, R0); PROC(E1.y, H1, R1); PROC(E2.y, H2, R2); PROC(E3.y, H3, R3);
    PROC(E4.y, H4, R4); PROC(E5.y, H5, R5); PROC(E6.y, H6, R6); PROC(E7.y, H7, R7);
    p += 8;
    rem -= nb << 3;
  }
  if (rem >= 4) {
    int2 E0 = ep[p], E1 = ep[p + 1], E2 = ep[p + 2], E3 = ep[p + 3];
    __half2 H0, H1, H2, H3, R0, R1, R2, R3;
    ROWS(E0.x, H0, R0); ROWS(E1.x, H1, R1); ROWS(E2.x, H2, R2); ROWS(E3.x, H3, R3);
    PROC(E0.y, H0, R0); PROC(E1.y, H1, R1); PROC(E2.y, H2, R2); PROC(E3.y, H3, R3);
    p += 4; rem -= 4;
  }
  for (; rem > 0; --rem, ++p) {
    int2 e = ep[p];
    __half2 hv, rv;
    ROWS(e.x, hv, rv);
    PROC(e.y, hv, rv);
  }
#undef ROWS
#undef PROC
  const float invc = 1.0f / (float)(cnn + 1);
  const float mean0 = sa0 * invc, mean1 = sa1 * invc;
  const float sd0 = sqrtf(fmaxf(qa0 * invc - mean0 * mean0, EPSF));
  const float sd1 = sqrtf(fmaxf(qa1 * invc - mean1 * mean1, EPSF));
  sh[wid][lane]       = __floats2half2_rn(mean0, mean1);
  sh[wid][64 + lane]  = __floats2half2_rn(mx0, mx1);
  sh[wid][128 + lane] = __floats2half2_rn(mn0, mn1);
  sh[wid][192 + lane] = __floats2half2_rn(sd0, sd1);
  __syncthreads();
  if (threadIdx.x >= 64) return;
  mfma_epilogue<LAST>((const _Float16*)&sh[0][0], (const _Float16*)hin2, houth,
                      lg, logsum, Wm, bias, query, h_index, nbase, lane, false,
                      W1m, b1, W2, b2, out, hbuf);
}

extern "C" void kernel_launch(void* const* d_in, const int* in_sizes, int n_in,
                              void* d_out, int out_size, void* d_ws, size_t ws_size,
                              hipStream_t stream) {
  const int*   node_in  = (const int*)d_in[0];
  const int*   node_out = (const int*)d_in[1];
  const int*   relation = (const int*)d_in[2];
  const float* ew       = (const float*)d_in[3];
  const int*   h_index  = (const int*)d_in[4];
  const int*   r_index  = (const int*)d_in[5];
  const float* qemb     = (const float*)d_in[6];
  const float* relW     = (const float*)d_in[7];
  const float* relB     = (const float*)d_in[8];
  const float* linW     = (const float*)d_in[9];
  const float* linB     = (const float*)d_in[10];
  const float* W1       = (const float*)d_in[11];
  const float* b1       = (const float*)d_in[12];
  const float* W2       = (const float*)d_in[13];
  const float* b2       = (const float*)d_in[14];
  float* out = (float*)d_out;

  char* ws = (char*)d_ws;
  size_t off = 0;
  auto alloc = [&](size_t bytes) -> char* {
    char* p = ws + off;
    off += (bytes + 255) & ~(size_t)255;
    return p;
  };
  __half*   h0     = (__half*)  alloc((size_t)NN * BD * 2);
  __half*   h1buf  = (__half*)  alloc((size_t)NN * BD * 2);
  __half*   relIn  = (__half*)  alloc((size_t)LL * R2C * BD * 2);
  _Float16* Wm     = (_Float16*)alloc((size_t)LL * WMH * 2);
  _Float16* W1m    = (_Float16*)alloc((size_t)4096 * 2);
  int2*     ep     = (int2*)    alloc((size_t)NN * CAP * 8);
  int*      cw     = (int*)     alloc((size_t)NN * 8);   // cnti | wsum
  float*    stats  = (float*)   alloc(256);   // [0]=logsum (contiguous w/ cw)
  float*    lg     = (float*)   alloc((size_t)NN * 4);
  float*    query  = (float*)   alloc((size_t)BD * 4);

  int*   cnti = cw;
  float* wsum = (float*)(cw + NN);
  float* logsum = stats;

  // cw and stats are contiguous (both 256-padded): one memset clears both
  hipMemsetAsync(cw, 0, (size_t)NN * 8 + 256, stream);

  build_setup_kernel<<<NEB + NWMB + NRELIN + NW1P + 1, 256, 0, stream>>>(
      node_in, node_out, relation, ew, cnti, wsum, ep,
      linW, Wm, r_index, qemb, relW, relB, relIn, query, W1, W1m);
  lg_kernel<<<(NN + 255) / 256, 256, 0, stream>>>(wsum, lg, logsum);

  __half* hin = h0; __half* hout = h1buf;
  for (int l = 0; l < LL; ++l) {
    if (l == 0) {
      layer1_fused_kernel<<<NN / 4, 256, 0, stream>>>(
          (const __half2*)relIn, ep, cnti, h_index, query, lg, logsum,
          Wm, linB, hout);
    } else if (l < LL - 1) {
      layer_fused_kernel<false><<<NN / 4, 256, 0, stream>>>(
          (const __half2*)hin, (const __half2*)relIn + (size_t)l * R2C * 64,
          ep, cnti, h_index, query, lg, logsum,
          Wm + (size_t)l * WMH, linB + (size_t)l * DD, hout,
          nullptr, nullptr, nullptr, nullptr, nullptr);
    } else {
      layer_fused_kernel<true><<<NN / 4, 256, 0, stream>>>(
          (const __half2*)hin, (const __half2*)relIn + (size_t)l * R2C * 64,
          ep, cnti, h_index, query, lg, logsum,
          Wm + (size_t)l * WMH, linB + (size_t)l * DD, hout,
          W1m, b1, W2, b2, out);
    }
    __half* tmp = hin; hin = hout; hout = tmp;
  }
}

// Round 3
// 271.419 us; speedup vs baseline: 1.0882x; 1.0882x over previous
//
#include <hip/hip_runtime.h>
#include <hip/hip_fp16.h>

#define NN  25000
#define EE  500000
#define BB  4
#define DD  32
#define LL  4
#define R2C 474
#define BD  128      // B*D
#define THD 416      // 13*D
#define EPSF 1e-6f
#define WMH 13312    // halfs per layer of MFMA-packed W: 13 t * 2 nt * 64 * 8
#define CAP 64       // fixed CSR segment capacity (max degree ~45 for Poisson(20))

// merged build+setup grid partition
#define NEB    245   // ceil(EE/8 / 256), 8 edges/thread
#define NWMB   208   // LL*WMH / 256
#define NRELIN 948   // LL*R2C*BD / 256
#define NW1P   16    // 4096 / 256

typedef _Float16 half8 __attribute__((ext_vector_type(8)));
typedef float    f32x4 __attribute__((ext_vector_type(4)));

// ---------------- merged graph build + all query-side setup ----------------
// blocks [0,NEB)        : 8 edges/thread: slot atomic + direct CSR scatter
// blocks [NEB,+NWMB)    : pack lin_W into MFMA B-fragment order (fp16)
// blocks [..,+NRELIN)   : rel_in for ALL layers (query recomputed inline)
// blocks [..,+NW1P)     : pack mlp_W1 into MFMA B-fragment order (fp16)
// last block            : query gather
__global__ __launch_bounds__(256) void build_setup_kernel(
    const int* __restrict__ node_in, const int* __restrict__ node_out,
    const int* __restrict__ relation, const float* __restrict__ ew,
    int* __restrict__ cnt, int2* __restrict__ ep,
    const float* __restrict__ linW, _Float16* __restrict__ Wm,
    const int* __restrict__ r_index, const float* __restrict__ qemb,
    const float* __restrict__ relW, const float* __restrict__ relB,
    __half* __restrict__ relIn, float* __restrict__ query,
    const float* __restrict__ W1, _Float16* __restrict__ W1m) {
  const int blk = blockIdx.x;
  const int tid = threadIdx.x;
  if (blk < NEB) {
    int i = blk * 256 + tid;                     // edge-octet index
    if (i >= EE / 8) return;
    const int4*   ni4 = (const int4*)node_in;
    const int4*   no4 = (const int4*)node_out;
    const int4*   rl4 = (const int4*)relation;
    const float4* ew4 = (const float4*)ew;
    int4   noA = no4[2 * i], noB = no4[2 * i + 1];
    int4   niA = ni4[2 * i], niB = ni4[2 * i + 1];
    int4   rlA = rl4[2 * i], rlB = rl4[2 * i + 1];
    float4 ewA = ew4[2 * i], ewB = ew4[2 * i + 1];
    // 8 independent returning atomics in flight
    int s0 = atomicAdd(&cnt[noA.x], 1);
    int s1 = atomicAdd(&cnt[noA.y], 1);
    int s2 = atomicAdd(&cnt[noA.z], 1);
    int s3 = atomicAdd(&cnt[noA.w], 1);
    int s4 = atomicAdd(&cnt[noB.x], 1);
    int s5 = atomicAdd(&cnt[noB.y], 1);
    int s6 = atomicAdd(&cnt[noB.z], 1);
    int s7 = atomicAdd(&cnt[noB.w], 1);
    ep[noA.x * CAP + s0] = make_int2(niA.x | (rlA.x << 15), __float_as_int(ewA.x));
    ep[noA.y * CAP + s1] = make_int2(niA.y | (rlA.y << 15), __float_as_int(ewA.y));
    ep[noA.z * CAP + s2] = make_int2(niA.z | (rlA.z << 15), __float_as_int(ewA.z));
    ep[noA.w * CAP + s3] = make_int2(niA.w | (rlA.w << 15), __float_as_int(ewA.w));
    ep[noB.x * CAP + s4] = make_int2(niB.x | (rlB.x << 15), __float_as_int(ewB.x));
    ep[noB.y * CAP + s5] = make_int2(niB.y | (rlB.y << 15), __float_as_int(ewB.y));
    ep[noB.z * CAP + s6] = make_int2(niB.z | (rlB.z << 15), __float_as_int(ewB.z));
    ep[noB.w * CAP + s7] = make_int2(niB.w | (rlB.w << 15), __float_as_int(ewB.w));
  } else if (blk < NEB + NWMB) {
    int idx = (blk - NEB) * 256 + tid;           // < LL*WMH exactly
    int l = idx / WMH, rest = idx % WMH;
    int t = rest >> 10;
    int nt = (rest >> 9) & 1;
    int L = (rest >> 3) & 63;
    int j = rest & 7;
    int k = t * 32 + (L >> 4) * 8 + j;
    int n = nt * 16 + (L & 15);
    int wrow;
    if (k < 32) wrow = k;
    else {
      int kk = k - 32;
      int slab = kk >> 7, s = (kk >> 5) & 3, dd = kk & 31;
      wrow = DD + (dd * 4 + s) * 3 + slab;
    }
    Wm[idx] = (_Float16)linW[(size_t)l * THD * DD + (size_t)wrow * DD + n];
  } else if (blk < NEB + NWMB + NRELIN) {
    int o = (blk - NEB - NWMB) * 256 + tid;      // < LL*R2C*BD exactly
    int l = o / (R2C * BD);
    int rest = o % (R2C * BD);
    int r = rest >> 7, b = (rest >> 5) & 3, d = rest & 31;
    int col = r * DD + d;
    const float* W = relW + (size_t)l * DD * R2C * DD;
    const float* qrow = qemb + (size_t)r_index[b] * DD;
    float acc = relB[(size_t)l * R2C * DD + col];
    #pragma unroll
    for (int k = 0; k < DD; ++k)
      acc = fmaf(qrow[k], W[(size_t)k * (R2C * DD) + col], acc);
    relIn[o] = __float2half(acc);
  } else if (blk < NEB + NWMB + NRELIN + NW1P) {
    int idx = (blk - NEB - NWMB - NRELIN) * 256 + tid;  // < 4096 exactly
    int kc = idx >> 11;
    int nt = (idx >> 9) & 3;
    int L = (idx >> 3) & 63;
    int j = idx & 7;
    int k = kc * 32 + (L >> 4) * 8 + j;          // feat row 0..63
    int c = nt * 16 + (L & 15);                  // out col 0..63
    W1m[idx] = (_Float16)W1[(size_t)k * (2 * DD) + c];
  } else {
    if (tid < BD) query[tid] = qemb[(size_t)r_index[tid >> 5] * DD + (tid & 31)];
  }
}

// log-degree + logsum reduce; weighted degree recomputed from CSR segments
// (removes 500K wsum atomics from the build kernel)
__global__ __launch_bounds__(256) void lg_kernel(const int* __restrict__ cnt,
                                                 const int2* __restrict__ ep,
                                                 float* __restrict__ lg,
                                                 float* __restrict__ logsum) {
  int n = blockIdx.x * 256 + threadIdx.x;
  float v = 0.f;
  if (n < NN) {
    int c = cnt[n];
    const int2* seg = ep + (size_t)n * CAP;
    float s = 0.f;
    for (int i = 0; i < c; ++i) s += __int_as_float(seg[i].y);
    v = logf(s + 1.0f);
    lg[n] = v;
  }
  __shared__ float red[256];
  red[threadIdx.x] = v; __syncthreads();
  for (int o = 128; o > 0; o >>= 1) {
    if (threadIdx.x < o) red[threadIdx.x] += red[threadIdx.x + o];
    __syncthreads();
  }
  if (threadIdx.x == 0) atomicAdd(logsum, red[0]);
}

// ---- shared MFMA epilogue: one wave computes 16x32 linear for 4 nodes ----
// sh layout: [nl][s*128 + b*32 + d] halfs (s = mean,max,min,std).
// hzero: if true, t=0 A-fragment is analytic boundary (layer 1).
// LAST: fuse the final MLP (feat=[hidden,query] -> relu(64) -> 1) and write
//       scores directly; skip the hidden store.
template <bool LAST>
__device__ __forceinline__ void mfma_epilogue(const _Float16* sh,
                                              const _Float16* hinh,
                                              __half* houth,
                                              const float* lg,
                                              const float* logsum,
                                              const _Float16* Wm,
                                              const float* bias,
                                              const float* query,
                                              const int* h_index,
                                              int nbase, int lane, bool hzero,
                                              const _Float16* W1m,
                                              const float* b1,
                                              const float* W2,
                                              const float* b2,
                                              float* out,
                                              _Float16* hbuf) {
  const int m = lane & 15;
  const int q = lane >> 4;
  const int nl = m >> 2;
  const int n = nbase + nl;
  const int b = m & 3;
  const float sc = lg[n] * ((float)NN / logsum[0]);
  const _Float16 one = (_Float16)1.f;
  const _Float16 s1h = (_Float16)sc;
  const _Float16 s2h = (_Float16)(1.0f / fmaxf(sc, 0.01f));
  const _Float16* ssrc = sh + nl * 512 + b * 32 + q * 8;

  f32x4 c0 = {0.f, 0.f, 0.f, 0.f};
  f32x4 c1 = {0.f, 0.f, 0.f, 0.f};
  half8 a;
  if (hzero) {
    a = (half8)(_Float16)0.f;
    if (n == h_index[b]) {
      const float* qp = query + b * 32 + q * 8;
      #pragma unroll
      for (int j = 0; j < 8; ++j) a[j] = (_Float16)qp[j];
    }
  } else {
    a = *(const half8*)(hinh + (unsigned)n * BD + b * 32 + q * 8);
  }
  #pragma unroll
  for (int t = 0; t < 13; ++t) {
    if (t > 0) {
      const int slab = (t - 1) >> 2, s = (t - 1) & 3;
      a = *(const half8*)(ssrc + s * 128);
      const _Float16 sch = (slab == 0) ? one : ((slab == 1) ? s1h : s2h);
      half8 sv = {sch, sch, sch, sch, sch, sch, sch, sch};
      a = a * sv;
    }
    half8 b0 = *(const half8*)(Wm + (unsigned)(t * 2 + 0) * 512 + lane * 8);
    half8 b1f = *(const half8*)(Wm + (unsigned)(t * 2 + 1) * 512 + lane * 8);
    c0 = __builtin_amdgcn_mfma_f32_16x16x32_f16(a, b0, c0, 0, 0, 0);
    c1 = __builtin_amdgcn_mfma_f32_16x16x32_f16(a, b1f, c1, 0, 0, 0);
  }
  const int col = lane & 15;
  const float bj0 = bias[col], bj1 = bias[col + 16];
  if constexpr (!LAST) {
    #pragma unroll
    for (int i = 0; i < 4; ++i) {
      const int mr = q * 4 + i;
      __half* dst = houth + (unsigned)(nbase + (mr >> 2)) * BD + (mr & 3) * 32 + col;
      dst[0]  = __float2half(fmaxf(c0[i] + bj0, 0.f));
      dst[16] = __float2half(fmaxf(c1[i] + bj1, 0.f));
    }
  } else {
    // stage relu'd hidden (C-layout) into LDS for transpose into A-layout
    #pragma unroll
    for (int i = 0; i < 4; ++i) {
      const int mr = q * 4 + i;
      hbuf[mr * 32 + col]      = (_Float16)fmaxf(c0[i] + bj0, 0.f);
      hbuf[mr * 32 + 16 + col] = (_Float16)fmaxf(c1[i] + bj1, 0.f);
    }
    // A-fragment reads: row = lane&15 (node,b), k = q*8+j
    half8 ah = *(const half8*)(hbuf + m * 32 + q * 8);
    half8 aq;
    const float* qp = query + b * 32 + q * 8;
    #pragma unroll
    for (int j = 0; j < 8; ++j) aq[j] = (_Float16)qp[j];
    f32x4 h1c[4];
    #pragma unroll
    for (int nt = 0; nt < 4; ++nt) {
      h1c[nt] = (f32x4){0.f, 0.f, 0.f, 0.f};
      half8 w0 = *(const half8*)(W1m + (unsigned)(0 * 4 + nt) * 512 + lane * 8);
      half8 w1 = *(const half8*)(W1m + (unsigned)(1 * 4 + nt) * 512 + lane * 8);
      h1c[nt] = __builtin_amdgcn_mfma_f32_16x16x32_f16(ah, w0, h1c[nt], 0, 0, 0);
      h1c[nt] = __builtin_amdgcn_mfma_f32_16x16x32_f16(aq, w1, h1c[nt], 0, 0, 0);
    }
    float part[4] = {0.f, 0.f, 0.f, 0.f};
    #pragma unroll
    for (int nt = 0; nt < 4; ++nt) {
      const float bb = b1[nt * 16 + col];
      const float ww = W2[nt * 16 + col];
      #pragma unroll
      for (int i = 0; i < 4; ++i) {
        float v = fmaxf(h1c[nt][i] + bb, 0.f);
        part[i] = fmaf(v, ww, part[i]);
      }
    }
    #pragma unroll
    for (int i = 0; i < 4; ++i) {
      part[i] += __shfl_xor(part[i], 1);
      part[i] += __shfl_xor(part[i], 2);
      part[i] += __shfl_xor(part[i], 4);
      part[i] += __shfl_xor(part[i], 8);
    }
    if (col == 0) {
      const float b2v = b2[0];
      #pragma unroll
      for (int i = 0; i < 4; ++i)
        out[(unsigned)i * NN + nbase + q] = part[i] + b2v;
    }
  }
}

// ---------------- fused layer 1: analytic sparse gather + MFMA linear ------
__global__ __launch_bounds__(256) void layer1_fused_kernel(
    const __half2* __restrict__ rel2, const int2* __restrict__ ep,
    const int* __restrict__ cnt, const int* __restrict__ h_index,
    const float* __restrict__ query, const float* __restrict__ lg,
    const float* __restrict__ logsum, const _Float16* __restrict__ Wm,
    const float* __restrict__ bias, __half* __restrict__ houth) {
  __shared__ __align__(16) __half2 sh[4][256];   // [wave][s*64 + lane]
  const int lane = threadIdx.x & 63;
  const int wid  = threadIdx.x >> 6;
  const int nbase = blockIdx.x * 4;
  const int n = nbase + wid;
  const int b = lane >> 4;
  const int d0 = (lane & 15) * 2;
  const float q0 = query[b * 32 + d0], q1 = query[b * 32 + d0 + 1];
  const int hb = h_index[b];
  const int beg = n * CAP;
  const int cnn = __builtin_amdgcn_readfirstlane(cnt[n]);
  const float mb0 = (n == hb) ? q0 : 0.f;
  const float mb1 = (n == hb) ? q1 : 0.f;
  float sa0 = mb0, qa0 = mb0 * mb0, mx0 = mb0, mn0 = mb0;
  float sa1 = mb1, qa1 = mb1 * mb1, mx1 = mb1, mn1 = mb1;
  int matched = 0;
  for (int p = beg; p < beg + cnn; ++p) {
    int2 e = ep[p];
    if ((e.x & 0x7fff) == hb) {
      __half2 rv = rel2[(unsigned)((unsigned)e.x >> 15) * 64 + lane];
      float w = __int_as_float(e.y);
      float2 rf = __half22float2(rv);
      float m0 = rf.x * q0, mw0 = m0 * w;
      float m1 = rf.y * q1, mw1 = m1 * w;
      sa0 += mw0; qa0 = fmaf(m0, mw0, qa0); mx0 = fmaxf(mx0, mw0); mn0 = fminf(mn0, mw0);
      sa1 += mw1; qa1 = fmaf(m1, mw1, qa1); mx1 = fmaxf(mx1, mw1); mn1 = fminf(mn1, mw1);
      ++matched;
    }
  }
  if (matched < cnn) {
    mx0 = fmaxf(mx0, 0.f); mn0 = fminf(mn0, 0.f);
    mx1 = fmaxf(mx1, 0.f); mn1 = fminf(mn1, 0.f);
  }
  const float invc = 1.0f / (float)(cnn + 1);
  const float mean0 = sa0 * invc, mean1 = sa1 * invc;
  const float sd0 = sqrtf(fmaxf(qa0 * invc - mean0 * mean0, EPSF));
  const float sd1 = sqrtf(fmaxf(qa1 * invc - mean1 * mean1, EPSF));
  sh[wid][lane]       = __floats2half2_rn(mean0, mean1);
  sh[wid][64 + lane]  = __floats2half2_rn(mx0, mx1);
  sh[wid][128 + lane] = __floats2half2_rn(mn0, mn1);
  sh[wid][192 + lane] = __floats2half2_rn(sd0, sd1);
  __syncthreads();
  if (threadIdx.x >= 64) return;
  mfma_epilogue<false>((const _Float16*)&sh[0][0], nullptr, houth, lg, logsum,
                       Wm, bias, query, h_index, nbase, lane, true,
                       nullptr, nullptr, nullptr, nullptr, nullptr, nullptr);
}

// ---------------- fused generic layer: gather + MFMA linear ----------------
template <bool LAST>
__global__ __launch_bounds__(256) void layer_fused_kernel(
    const __half2* __restrict__ hin2, const __half2* __restrict__ rel2,
    const int2* __restrict__ ep, const int* __restrict__ cnt,
    const int* __restrict__ h_index, const float* __restrict__ query,
    const float* __restrict__ lg, const float* __restrict__ logsum,
    const _Float16* __restrict__ Wm, const float* __restrict__ bias,
    __half* __restrict__ houth,
    const _Float16* __restrict__ W1m, const float* __restrict__ b1,
    const float* __restrict__ W2, const float* __restrict__ b2,
    float* __restrict__ out) {
  __shared__ __align__(16) __half2 sh[4][256];
  __shared__ __align__(16) _Float16 hbuf[512];
  const int lane = threadIdx.x & 63;
  const int wid  = threadIdx.x >> 6;
  const int nbase = blockIdx.x * 4;
  const int n = nbase + wid;
  const int b = lane >> 4;
  const int d0 = (lane & 15) * 2;
  const float q0 = query[b * 32 + d0], q1 = query[b * 32 + d0 + 1];
  const int hb = h_index[b];
  const int beg = n * CAP;
  const int cnn = __builtin_amdgcn_readfirstlane(cnt[n]);
  const float mb0 = (n == hb) ? q0 : 0.f;
  const float mb1 = (n == hb) ? q1 : 0.f;
  float sa0 = mb0, qa0 = mb0 * mb0, mx0 = mb0, mn0 = mb0;
  float sa1 = mb1, qa1 = mb1 * mb1, mx1 = mb1, mn1 = mb1;

#define PROC(Ez, Hv, Rv) {                                                   \
    float w = __int_as_float(Ez);                                            \
    float2 hf = __half22float2(Hv), rf = __half22float2(Rv);                 \
    float m0 = rf.x * hf.x, mw0 = m0 * w;                                    \
    float m1 = rf.y * hf.y, mw1 = m1 * w;                                    \
    sa0 += mw0; qa0 = fmaf(m0, mw0, qa0);                                    \
    mx0 = fmaxf(mx0, mw0); mn0 = fminf(mn0, mw0);                            \
    sa1 += mw1; qa1 = fmaf(m1, mw1, qa1);                                    \
    mx1 = fmaxf(mx1, mw1); mn1 = fminf(mn1, mw1); }
#define ROWS(Ex, Hd, Rd) {                                                   \
    Hd = hin2[(unsigned)((Ex) & 0x7fff) * 64 + lane];                        \
    Rd = rel2[(unsigned)((unsigned)(Ex) >> 15) * 64 + lane]; }

  int p = beg;
  int rem = cnn;
  const int nb = rem >> 3;
  if (nb > 0) {
    int2 E0, E1, E2, E3, E4, E5, E6, E7;
    __half2 H0, H1, H2, H3, H4, H5, H6, H7;
    __half2 R0, R1, R2, R3, R4, R5, R6, R7;
    E0 = ep[p];     E1 = ep[p + 1]; E2 = ep[p + 2]; E3 = ep[p + 3];
    E4 = ep[p + 4]; E5 = ep[p + 5]; E6 = ep[p + 6]; E7 = ep[p + 7];
    ROWS(E0.x, H0, R0); ROWS(E1.x, H1, R1); ROWS(E2.x, H2, R2); ROWS(E3.x, H3, R3);
    ROWS(E4.x, H4, R4); ROWS(E5.x, H5, R5); ROWS(E6.x, H6, R6); ROWS(E7.x, H7, R7);
    for (int it = 1; it < nb; ++it) {
      const int pn = p + 8;
      int2 F0 = ep[pn],     F1 = ep[pn + 1], F2 = ep[pn + 2], F3 = ep[pn + 3];
      int2 F4 = ep[pn + 4], F5 = ep[pn + 5], F6 = ep[pn + 6], F7 = ep[pn + 7];
      __half2 G0, G1, G2, G3, G4, G5, G6, G7;
      __half2 S0, S1, S2, S3, S4, S5, S6, S7;
      ROWS(F0.x, G0, S0); ROWS(F1.x, G1, S1); ROWS(F2.x, G2, S2); ROWS(F3.x, G3, S3);
      ROWS(F4.x, G4, S4); ROWS(F5.x, G5, S5); ROWS(F6.x, G6, S6); ROWS(F7.x, G7, S7);
      PROC(E0.y, H0, R0); PROC(E1.y, H1, R1); PROC(E2.y, H2, R2); PROC(E3.y, H3, R3);
      PROC(E4.y, H4, R4); PROC(E5.y, H5, R5); PROC(E6.y, H6, R6); PROC(E7.y, H7, R7);
      E0 = F0; E1 = F1; E2 = F2; E3 = F3; E4 = F4; E5 = F5; E6 = F6; E7 = F7;
      H0 = G0; H1 = G1; H2 = G2; H3 = G3; H4 = G4; H5 = G5; H6 = G6; H7 = G7;
      R0 = S0; R1 = S1; R2 = S2; R3 = S3; R4 = S4; R5 = S5; R6 = S6; R7 = S7;
      p = pn;
    }
    PROC(E0.y, H0, R0); PROC(E1.y, H1, R1); PROC(E2.y, H2, R2); PROC(E3.y, H3, R3);
    PROC(E4.y, H4, R4); PROC(E5.y, H5, R5); PROC(E6.y, H6, R6); PROC(E7.y, H7, R7);
    p += 8;
    rem -= nb << 3;
  }
  if (rem >= 4) {
    int2 E0 = ep[p], E1 = ep[p + 1], E2 = ep[p + 2], E3 = ep[p + 3];
    __half2 H0, H1, H2, H3, R0, R1, R2, R3;
    ROWS(E0.x, H0, R0); ROWS(E1.x, H1, R1); ROWS(E2.x, H2, R2); ROWS(E3.x, H3, R3);
    PROC(E0.y, H0, R0); PROC(E1.y, H1, R1); PROC(E2.y, H2, R2); PROC(E3.y, H3, R3);
    p += 4; rem -= 4;
  }
  for (; rem > 0; --rem, ++p) {
    int2 e = ep[p];
    __half2 hv, rv;
    ROWS(e.x, hv, rv);
    PROC(e.y, hv, rv);
  }
#undef ROWS
#undef PROC
  const float invc = 1.0f / (float)(cnn + 1);
  const float mean0 = sa0 * invc, mean1 = sa1 * invc;
  const float sd0 = sqrtf(fmaxf(qa0 * invc - mean0 * mean0, EPSF));
  const float sd1 = sqrtf(fmaxf(qa1 * invc - mean1 * mean1, EPSF));
  sh[wid][lane]       = __floats2half2_rn(mean0, mean1);
  sh[wid][64 + lane]  = __floats2half2_rn(mx0, mx1);
  sh[wid][128 + lane] = __floats2half2_rn(mn0, mn1);
  sh[wid][192 + lane] = __floats2half2_rn(sd0, sd1);
  __syncthreads();
  if (threadIdx.x >= 64) return;
  mfma_epilogue<LAST>((const _Float16*)&sh[0][0], (const _Float16*)hin2, houth,
                      lg, logsum, Wm, bias, query, h_index, nbase, lane, false,
                      W1m, b1, W2, b2, out, hbuf);
}

extern "C" void kernel_launch(void* const* d_in, const int* in_sizes, int n_in,
                              void* d_out, int out_size, void* d_ws, size_t ws_size,
                              hipStream_t stream) {
  const int*   node_in  = (const int*)d_in[0];
  const int*   node_out = (const int*)d_in[1];
  const int*   relation = (const int*)d_in[2];
  const float* ew       = (const float*)d_in[3];
  const int*   h_index  = (const int*)d_in[4];
  const int*   r_index  = (const int*)d_in[5];
  const float* qemb     = (const float*)d_in[6];
  const float* relW     = (const float*)d_in[7];
  const float* relB     = (const float*)d_in[8];
  const float* linW     = (const float*)d_in[9];
  const float* linB     = (const float*)d_in[10];
  const float* W1       = (const float*)d_in[11];
  const float* b1       = (const float*)d_in[12];
  const float* W2       = (const float*)d_in[13];
  const float* b2       = (const float*)d_in[14];
  float* out = (float*)d_out;

  char* ws = (char*)d_ws;
  size_t off = 0;
  auto alloc = [&](size_t bytes) -> char* {
    char* p = ws + off;
    off += (bytes + 255) & ~(size_t)255;
    return p;
  };
  __half*   h0     = (__half*)  alloc((size_t)NN * BD * 2);
  __half*   h1buf  = (__half*)  alloc((size_t)NN * BD * 2);
  __half*   relIn  = (__half*)  alloc((size_t)LL * R2C * BD * 2);
  _Float16* Wm     = (_Float16*)alloc((size_t)LL * WMH * 2);
  _Float16* W1m    = (_Float16*)alloc((size_t)4096 * 2);
  int2*     ep     = (int2*)    alloc((size_t)NN * CAP * 8);
  int*      cnti   = (int*)     alloc((size_t)NN * 4);
  float*    stats  = (float*)   alloc(256);   // [0]=logsum (contiguous w/ cnti)
  float*    lg     = (float*)   alloc((size_t)NN * 4);
  float*    query  = (float*)   alloc((size_t)BD * 4);

  float* logsum = stats;

  // cnti and stats are contiguous (cnti padded to 256): one memset clears both
  hipMemsetAsync(cnti, 0, (((size_t)NN * 4 + 255) & ~(size_t)255) + 256, stream);

  build_setup_kernel<<<NEB + NWMB + NRELIN + NW1P + 1, 256, 0, stream>>>(
      node_in, node_out, relation, ew, cnti, ep,
      linW, Wm, r_index, qemb, relW, relB, relIn, query, W1, W1m);
  lg_kernel<<<(NN + 255) / 256, 256, 0, stream>>>(cnti, ep, lg, logsum);

  __half* hin = h0; __half* hout = h1buf;
  for (int l = 0; l < LL; ++l) {
    if (l == 0) {
      layer1_fused_kernel<<<NN / 4, 256, 0, stream>>>(
          (const __half2*)relIn, ep, cnti, h_index, query, lg, logsum,
          Wm, linB, hout);
    } else if (l < LL - 1) {
      layer_fused_kernel<false><<<NN / 4, 256, 0, stream>>>(
          (const __half2*)hin, (const __half2*)relIn + (size_t)l * R2C * 64,
          ep, cnti, h_index, query, lg, logsum,
          Wm + (size_t)l * WMH, linB + (size_t)l * DD, hout,
          nullptr, nullptr, nullptr, nullptr, nullptr);
    } else {
      layer_fused_kernel<true><<<NN / 4, 256, 0, stream>>>(
          (const __half2*)hin, (const __half2*)relIn + (size_t)l * R2C * 64,
          ep, cnti, h_index, query, lg, logsum,
          Wm + (size_t)l * WMH, linB + (size_t)l * DD, hout,
          W1m, b1, W2, b2, out);
    }
    __half* tmp = hin; hin = hout; hout = tmp;
  }
}